// Round 1
// baseline (710.796 us; speedup 1.0000x reference)
//
#include <hip/hip_runtime.h>
#include <stdint.h>

// SparseConv3d: x [4,64,64,64,64] f32, w [64,64,3,3,3] f32 -> out [4,64,64,64,64] f32
// out = conv3d_SAME(x, w) masked to voxels where any input channel is nonzero.
// Strategy: compact active voxels (spatially random ~30%) -> bf16 MFMA gather-GEMM
//   [N_active x 1728] * [1728 x 64], K ordered tap-major (27 taps x 64 ci).

#define R3 262144           // 64^3 spatial per batch
#define NVOX (4 * R3)       // 1048576 voxels total
#define WSW_ELEMS (27 * 2 * 4 * 64 * 8)   // 110592 swizzled weight bf16

typedef __attribute__((ext_vector_type(4))) float f32x4;
typedef __attribute__((ext_vector_type(8))) short short8;

static __device__ inline unsigned short f2bf(float f) {
    union { float f; unsigned u; } v; v.f = f;
    unsigned u = v.u;
    return (unsigned short)((u + 0x7fffu + ((u >> 16) & 1u)) >> 16);  // RNE
}

// ---- weight swizzle: B-fragment order for mfma_f32_16x16x32_bf16 ----
// B[k][n]: lane holds B[k=(lane>>4)*8+j][n=lane&15], j=0..7 contiguous (16B/lane).
// layout: [tap 27][kc 2][nt 4][lane 64][j 8]
__global__ void wprep(const float* __restrict__ w, unsigned short* __restrict__ wsw) {
    int e = blockIdx.x * 256 + threadIdx.x;
    if (e >= WSW_ELEMS) return;
    int j    = e & 7;
    int lane = (e >> 3) & 63;
    int nt   = (e >> 9) & 3;
    int kc   = (e >> 11) & 1;
    int tap  = e >> 12;                       // kz*9+ky*3+kx
    int co = nt * 16 + (lane & 15);
    int ci = kc * 32 + ((lane >> 4) * 8) + j;
    wsw[e] = f2bf(w[(co * 64 + ci) * 27 + tap]);
}

// ---- pass 1: transpose x -> channels-last bf16 x_t, mask + compaction ----
__global__ void __launch_bounds__(256) xprep(const float* __restrict__ x,
                                             unsigned int* __restrict__ xt_u32,
                                             int* __restrict__ list,
                                             int* __restrict__ count) {
    __shared__ unsigned int lds[256 * 33];    // [voxel 256][ci-pair 32], pad 33 -> 2-way only
    __shared__ unsigned int wcnt[4], wbase[4], bbase;
    int t = threadIdx.x;
    int v = blockIdx.x * 256 + t;             // blocks never straddle batch (256 | 262144)
    int b = v >> 18;
    int s = v & (R3 - 1);
    const float* xb = x + (size_t)b * (64 * R3) + s;
    bool active = false;
#pragma unroll
    for (int c2 = 0; c2 < 32; ++c2) {
        float f0 = xb[(size_t)(2 * c2) * R3];
        float f1 = xb[(size_t)(2 * c2 + 1) * R3];
        active |= (f0 != 0.f) | (f1 != 0.f);
        lds[t * 33 + c2] = (unsigned)f2bf(f0) | ((unsigned)f2bf(f1) << 16);
    }
    __syncthreads();
    // coalesced write-out: 8192 contiguous words per block
    unsigned int* dst = xt_u32 + (size_t)blockIdx.x * 8192;
#pragma unroll
    for (int i = 0; i < 32; ++i) {
        int g = i * 256 + t;                  // g == (g>>5)*32 + (g&31)
        dst[g] = lds[(g >> 5) * 33 + (g & 31)];
    }
    // compaction
    int lane = t & 63, w = t >> 6;
    unsigned long long bal = __ballot(active);
    if (lane == 0) wcnt[w] = (unsigned)__popcll(bal);
    __syncthreads();
    if (t == 0) {
        unsigned tot = 0;
        for (int i = 0; i < 4; ++i) { wbase[i] = tot; tot += wcnt[i]; }
        bbase = (unsigned)atomicAdd(count, (int)tot);
    }
    __syncthreads();
    if (active) {
        unsigned pos = bbase + wbase[w] + (unsigned)__popcll(bal & ((1ULL << lane) - 1ULL));
        list[pos] = v;
    }
}

// ---- pass 2: gather-GEMM, 64 voxels x 64 co per block, bf16 MFMA 16x16x32 ----
__global__ void __launch_bounds__(256) sconv_gemm(const unsigned short* __restrict__ xt,
                                                  const unsigned short* __restrict__ wsw,
                                                  const int* __restrict__ list,
                                                  const int* __restrict__ count_p,
                                                  float* __restrict__ out) {
    __shared__ __align__(16) unsigned short Alds[64 * 72];  // 64 rows x (64 + 8 pad) bf16
    __shared__ int vids[64];
    int count = *count_p;
    int base = blockIdx.x * 64;
    if (base >= count) return;
    int t = threadIdx.x;
    if (t < 64) {
        int idx = base + t;
        vids[t] = (idx < count) ? list[idx] : -1;
    }
    __syncthreads();

    int lane = t & 63, w = t >> 6;
    int mt0 = (w & 1) * 2, nt0 = (w >> 1) * 2;   // 2x2 wave tiles over 4x4 grid
    f32x4 acc[2][2] = {};

    // A staging: 4 threads per row, 32B each
    int srow = t >> 2;
    int scol = t & 3;
    int vid = vids[srow];
    bool vvalid = vid >= 0;
    int vx = vid & 63, vy = (vid >> 6) & 63, vz = (vid >> 12) & 63;
    int vbase = vid & ~(R3 - 1);                 // b*262144

    for (int tap = 0; tap < 27; ++tap) {
        int dz = tap / 9 - 1, dy = (tap / 3) % 3 - 1, dx = tap % 3 - 1;
        uint4 val0 = {0, 0, 0, 0}, val1 = {0, 0, 0, 0};
        if (vvalid) {
            int nz = vz + dz, ny = vy + dy, nx = vx + dx;
            if ((unsigned)nz < 64u && (unsigned)ny < 64u && (unsigned)nx < 64u) {
                long long ns = (long long)vbase + nz * 4096 + ny * 64 + nx;
                const uint4* src = (const uint4*)(xt + (size_t)ns * 64) + scol * 2;
                val0 = src[0];
                val1 = src[1];
            }
        }
        *(uint4*)&Alds[srow * 72 + scol * 16] = val0;
        *(uint4*)&Alds[srow * 72 + scol * 16 + 8] = val1;
        __syncthreads();

#pragma unroll
        for (int kc = 0; kc < 2; ++kc) {
            short8 bfr[2], afr[2];
#pragma unroll
            for (int n = 0; n < 2; ++n) {
                int nt = nt0 + n;
                bfr[n] = *(const short8*)(wsw +
                          (((size_t)(tap * 8 + kc * 4 + nt)) * 64 + lane) * 8);
            }
#pragma unroll
            for (int m = 0; m < 2; ++m) {
                int row = (mt0 + m) * 16 + (lane & 15);
                afr[m] = *(const short8*)&Alds[row * 72 + kc * 32 + (lane >> 4) * 8];
            }
#pragma unroll
            for (int m = 0; m < 2; ++m)
#pragma unroll
                for (int n = 0; n < 2; ++n)
                    acc[m][n] = __builtin_amdgcn_mfma_f32_16x16x32_bf16(
                        afr[m], bfr[n], acc[m][n], 0, 0, 0);
        }
        __syncthreads();
    }

    // epilogue: D[row=(lane>>4)*4+reg][col=lane&15] (m89-verified layout)
    int q = lane >> 4;
#pragma unroll
    for (int m = 0; m < 2; ++m) {
#pragma unroll
        for (int rg = 0; rg < 4; ++rg) {
            int row = (mt0 + m) * 16 + q * 4 + rg;
            if (base + row < count) {
                int vv = vids[row];
                int bb = vv >> 18;
                int sp = vv & (R3 - 1);
#pragma unroll
                for (int n = 0; n < 2; ++n) {
                    int co = (nt0 + n) * 16 + (lane & 15);
                    out[((size_t)(bb * 64 + co)) * R3 + sp] = acc[m][n][rg];
                }
            }
        }
    }
}

// ---- fallback (ws too small): dense fp32 direct conv, one (b,co,z,y) row per block ----
__global__ void __launch_bounds__(64) fallback_conv(const float* __restrict__ x,
                                                    const float* __restrict__ wt,
                                                    float* __restrict__ out) {
    __shared__ float rowb[66];
    int bid = blockIdx.x;
    int y = bid & 63, z = (bid >> 6) & 63, co = (bid >> 12) & 63, b = bid >> 18;
    int t = threadIdx.x;
    float acc = 0.f;
    bool active = false;
    for (int ci = 0; ci < 64; ++ci) {
        const float* xp = x + ((size_t)(b * 64 + ci)) * R3;
        const float* wp = wt + ((size_t)(co * 64 + ci)) * 27;
        for (int dz = -1; dz <= 1; ++dz) {
            int nz = z + dz;
            bool okz = (unsigned)nz < 64u;
            for (int dy = -1; dy <= 1; ++dy) {
                int ny = y + dy;
                bool ok = okz && ((unsigned)ny < 64u);
                float v = ok ? xp[nz * 4096 + ny * 64 + t] : 0.f;
                rowb[t + 1] = v;
                if (t == 0) { rowb[0] = 0.f; rowb[65] = 0.f; }
                __syncthreads();
                if (dz == 0 && dy == 0) active |= (rowb[t + 1] != 0.f);
                const float* wq = wp + (dz + 1) * 9 + (dy + 1) * 3;
                acc += rowb[t] * wq[0] + rowb[t + 1] * wq[1] + rowb[t + 2] * wq[2];
                __syncthreads();
            }
        }
    }
    out[((size_t)(b * 64 + co)) * R3 + z * 4096 + y * 64 + t] = active ? acc : 0.f;
}

extern "C" void kernel_launch(void* const* d_in, const int* in_sizes, int n_in,
                              void* d_out, int out_size, void* d_ws, size_t ws_size,
                              hipStream_t stream) {
    const float* x = (const float*)d_in[0];
    const float* w = (const float*)d_in[1];
    float* out = (float*)d_out;

    const size_t XT_BYTES  = (size_t)NVOX * 64 * 2;           // 128 MB bf16 channels-last
    const size_t LIST_OFF  = XT_BYTES;                        // 4 MB int list
    const size_t WSW_OFF   = LIST_OFF + (size_t)NVOX * 4;
    const size_t CNT_OFF   = WSW_OFF + (size_t)WSW_ELEMS * 2;
    const size_t NEED      = CNT_OFF + 256;

    if (ws_size < NEED) {
        fallback_conv<<<NVOX, 64, 0, stream>>>(x, w, out);
        return;
    }

    unsigned int*   xt   = (unsigned int*)d_ws;
    int*            list = (int*)((char*)d_ws + LIST_OFF);
    unsigned short* wsw  = (unsigned short*)((char*)d_ws + WSW_OFF);
    int*            cnt  = (int*)((char*)d_ws + CNT_OFF);

    hipMemsetAsync(cnt, 0, sizeof(int), stream);
    hipMemsetAsync(d_out, 0, (size_t)out_size * sizeof(float), stream);
    wprep<<<WSW_ELEMS / 256, 256, 0, stream>>>(w, wsw);
    xprep<<<NVOX / 256, 256, 0, stream>>>(x, xt, list, cnt);
    sconv_gemm<<<NVOX / 64, 256, 0, stream>>>((const unsigned short*)xt, wsw, list, cnt, out);
}